// Round 1
// 931.953 us; speedup vs baseline: 1.0984x; 1.0984x over previous
//
#include <hip/hip_runtime.h>
#include <stdint.h>

typedef __bf16 bf16x8 __attribute__((ext_vector_type(8)));
typedef float f32x16 __attribute__((ext_vector_type(16)));
typedef float f32x4 __attribute__((ext_vector_type(4)));

__device__ __forceinline__ unsigned short f2bf(float f) {
    unsigned int u = __float_as_uint(f);
    unsigned int r = (u + 0x7fffu + ((u >> 16) & 1u)) >> 16;
    return (unsigned short)r;
}
__device__ __forceinline__ float bf2f(unsigned int h) {
    return __uint_as_float(h << 16);
}

__device__ __forceinline__ void gld_lds16(const void* g, void* l) {
    __builtin_amdgcn_global_load_lds((const __attribute__((address_space(1))) void*)g,
                                     (__attribute__((address_space(3))) void*)l, 16, 0, 0);
}

// ---------------- feats f32 -> bf16 ----------------------------------------------------
__global__ __launch_bounds__(256) void k_cvt_feats(const float* __restrict__ src,
                                                   unsigned short* __restrict__ dst) {
    int g = blockIdx.x * 256 + threadIdx.x;
    float4 v = ((const float4*)src)[g];
    ushort4 o;
    o.x = f2bf(v.x); o.y = f2bf(v.y); o.z = f2bf(v.z); o.w = f2bf(v.w);
    ((ushort4*)dst)[g] = o;
}

// ---------------- ROI crop_and_resize(14) + 2x2 maxpool -> pooled bf16 [1024][25088] ----
__global__ __launch_bounds__(256) void k_roipool(const unsigned short* __restrict__ feats,
                                                 const float* __restrict__ props,
                                                 unsigned short* __restrict__ pooled) {
    int b = blockIdx.x;                 // 1024*49
    int r = b / 49;
    int cell = b - r * 49;
    int py = cell / 7, px = cell - py * 7;
    int c = threadIdx.x * 2;
    unsigned int* outp = (unsigned int*)(pooled + (size_t)r * 25088 + cell * 512 + c);
    if (r >= 1000) { *outp = 0u; return; }
    float y1 = props[r * 4 + 0], x1 = props[r * 4 + 1];
    float y2 = props[r * 4 + 2], x2 = props[r * 4 + 3];
    float sy = (y2 - y1) * (37.0f / 13.0f);
    float sx = (x2 - x1) * (49.0f / 13.0f);
    float m0 = -1e30f, m1 = -1e30f;
#pragma unroll
    for (int a = 0; a < 2; ++a) {
        float ys = y1 * 37.0f + (float)(2 * py + a) * sy;
        float y0f = floorf(ys);
        float wy = ys - y0f;
        int y0 = (int)y0f; y0 = min(max(y0, 0), 37);
        int y1i = min(y0 + 1, 37);
#pragma unroll
        for (int bb = 0; bb < 2; ++bb) {
            float xs = x1 * 49.0f + (float)(2 * px + bb) * sx;
            float x0f = floorf(xs);
            float wx = xs - x0f;
            int x0 = (int)x0f; x0 = min(max(x0, 0), 49);
            int x1i = min(x0 + 1, 49);
            unsigned int t00 = *(const unsigned int*)(feats + ((y0 * 50 + x0) * 512 + c));
            unsigned int t01 = *(const unsigned int*)(feats + ((y0 * 50 + x1i) * 512 + c));
            unsigned int t10 = *(const unsigned int*)(feats + ((y1i * 50 + x0) * 512 + c));
            unsigned int t11 = *(const unsigned int*)(feats + ((y1i * 50 + x1i) * 512 + c));
            float w00 = (1.f - wy) * (1.f - wx), w01 = (1.f - wy) * wx;
            float w10 = wy * (1.f - wx), w11 = wy * wx;
            float v0 = bf2f(t00 & 0xffffu) * w00 + bf2f(t01 & 0xffffu) * w01 +
                       bf2f(t10 & 0xffffu) * w10 + bf2f(t11 & 0xffffu) * w11;
            float v1 = bf2f(t00 >> 16) * w00 + bf2f(t01 >> 16) * w01 +
                       bf2f(t10 >> 16) * w10 + bf2f(t11 >> 16) * w11;
            m0 = fmaxf(m0, v0);
            m1 = fmaxf(m1, v1);
        }
    }
    *outp = ((unsigned int)f2bf(m1) << 16) | (unsigned int)f2bf(m0);
}

// ---------------- tiled transpose + f32->bf16: BT[n][k] = bf16(B[k][n]) ----------------
__global__ __launch_bounds__(256) void k_transpose_cvt(const float* __restrict__ B,
                                                       unsigned short* __restrict__ BT,
                                                       int K, int N) {
    __shared__ unsigned int tile[64][32];
    int k0 = blockIdx.x * 64;
    int n0 = blockIdx.y * 64;
    int t = threadIdx.x;
    int kr = (t >> 4) * 2;        // even k within tile: 0..30
    int c4 = (t & 15) * 4;        // n within tile
#pragma unroll
    for (int ii = 0; ii < 2; ++ii) {
        int k = kr + ii * 32;
        int kd = k >> 1;
        const float* p0 = B + (size_t)(k0 + k) * N + n0 + c4;
        float4 v0 = *(const float4*)p0;
        float4 v1 = *(const float4*)(p0 + N);
        float lo[4] = {v0.x, v0.y, v0.z, v0.w};
        float hi[4] = {v1.x, v1.y, v1.z, v1.w};
#pragma unroll
        for (int c = 0; c < 4; ++c) {
            int n = c4 + c;
            int dw = (((kd >> 1) ^ ((n >> 2) & 7)) << 1) | (kd & 1);
            tile[n][dw] = (unsigned)f2bf(lo[c]) | ((unsigned)f2bf(hi[c]) << 16);
        }
    }
    __syncthreads();
    int nl = t >> 2;
    int x = (nl >> 2) & 7;
    int pbase = (t & 3) * 4;      // original pair index base
    uint2 r[4];
#pragma unroll
    for (int q = 0; q < 4; ++q) {
        int p = (pbase + q) ^ x;
        r[q] = *(const uint2*)&tile[nl][p << 1];
    }
    unsigned short* dst = BT + (size_t)(n0 + nl) * K + k0 + (t & 3) * 16;
    uint4 o0, o1;
    o0.x = r[0].x; o0.y = r[0].y; o0.z = r[1].x; o0.w = r[1].y;
    o1.x = r[2].x; o1.y = r[2].y; o1.z = r[3].x; o1.w = r[3].y;
    *(uint4*)(dst + 0) = o0;
    *(uint4*)(dst + 8) = o1;
}

// ---------------- 256x256 8-phase bf16 GEMM, BK=64, counted vmcnt, split-K -------------
// A [M,K] bf16 rm; BT [N,K] bf16 rm; Cpart[z][M][N] f32 (overwritten, no atomics).
// 8 waves (2M x 4N), per-wave 128x64 out via 16x16x32 MFMA (8x4 frags).
// LDS 128 KiB: buf{0,1} x {A0,A1,B0,B1} halves of [128][64] bf16, chunk-XOR swizzled.
__global__ __launch_bounds__(512, 2) void k_gemm256(const unsigned short* __restrict__ A,
                                                    const unsigned short* __restrict__ BT,
                                                    float* __restrict__ Cpart,
                                                    int N, int K, int kChunk, int MN) {
    __shared__ __align__(16) char lds[131072];
    const int n0 = blockIdx.x * 256;
    const int m0 = blockIdx.y * 256;
    const int kBeg = blockIdx.z * kChunk;
    const int NT = kChunk >> 6;
    const int t = threadIdx.x;
    const int l = t & 63;
    const int wave = t >> 6;
    const int wrow = wave >> 2;   // 0..1 -> A half / 128-row block
    const int wcol = wave & 3;    // 0..3 -> 64-col block
    const int l15 = l & 15;
    const int lq = l >> 4;        // 0..3 k-octet
    const size_t rK = (size_t)K;

    // ds_read swizzled chunk offsets (bytes) for kh=0/1; row&7 == l&7 for all frags
    const int rowoff = l15 * 128;
    const int cb0 = ((lq ^ (l & 7)) << 4);
    const int cb1 = (((4 + lq) ^ (l & 7)) << 4);

    // staging: thread t -> LDS linear (row = q*64 + t>>3, chunk = t&7);
    // pre-swizzled global source chunk = (t&7) ^ (row&7)
    const int srow = t >> 3;
    const int sj = (t & 7) ^ (srow & 7);
    const unsigned short* agp = A + (size_t)(m0 + srow) * rK + sj * 8;
    const unsigned short* bgp = BT + (size_t)(n0 + srow) * rK + sj * 8;
    char* aldst = (char*)lds + t * 16;
    char* bldst = (char*)lds + 32768 + t * 16;

#define STAGE_A(bi, h, kt) do {                                                           \
        gld_lds16(agp + (size_t)((h) * 128) * rK + (kt), aldst + (bi) * 65536 + (h) * 16384);        \
        gld_lds16(agp + (size_t)((h) * 128 + 64) * rK + (kt), aldst + (bi) * 65536 + (h) * 16384 + 8192); \
    } while (0)
#define STAGE_B(bi, h, kt) do {                                                           \
        gld_lds16(bgp + (size_t)((h) * 128) * rK + (kt), bldst + (bi) * 65536 + (h) * 16384);        \
        gld_lds16(bgp + (size_t)((h) * 128 + 64) * rK + (kt), bldst + (bi) * 65536 + (h) * 16384 + 8192); \
    } while (0)

    f32x4 acc[8][4];
#pragma unroll
    for (int i = 0; i < 8; ++i)
#pragma unroll
        for (int j = 0; j < 4; ++j) acc[i][j] = (f32x4){0.f, 0.f, 0.f, 0.f};

    bf16x8 bB[4][2];
    bf16x8 aA[2][2];

    // prologue: tile0 fully + tile1 B halves; vmcnt(4) leaves tile1.B in flight
    STAGE_A(0, 0, kBeg); STAGE_A(0, 1, kBeg);
    STAGE_B(0, 0, kBeg); STAGE_B(0, 1, kBeg);
    STAGE_B(1, 0, kBeg + 64); STAGE_B(1, 1, kBeg + 64);
    asm volatile("s_waitcnt vmcnt(4)" ::: "memory");
    __builtin_amdgcn_s_barrier();

    int cur = 0;
    for (int tt = 0; tt < NT; ++tt) {
        const char* Ab = (const char*)lds + cur * 65536 + wrow * 16384 + rowoff;
        const char* Bb = (const char*)lds + cur * 65536 + 32768 + wcol * 8192 + rowoff;
        const int nx = cur ^ 1;
        const bool tn1 = (tt + 1 < NT);
        const bool tn2 = (tt + 2 < NT);
        const int k1 = kBeg + (tt + 1) * 64;
        const int k2 = kBeg + (tt + 2) * 64;
#pragma unroll
        for (int q = 0; q < 4; ++q) {
            // ds-load register subtile for this phase
            aA[0][0] = *(const bf16x8*)(Ab + (2 * q) * 2048 + cb0);
            aA[0][1] = *(const bf16x8*)(Ab + (2 * q) * 2048 + cb1);
            aA[1][0] = *(const bf16x8*)(Ab + (2 * q + 1) * 2048 + cb0);
            aA[1][1] = *(const bf16x8*)(Ab + (2 * q + 1) * 2048 + cb1);
            if (q == 0) {
#pragma unroll
                for (int nf = 0; nf < 4; ++nf) {
                    bB[nf][0] = *(const bf16x8*)(Bb + nf * 2048 + cb0);
                    bB[nf][1] = *(const bf16x8*)(Bb + nf * 2048 + cb1);
                }
            }
            // stage 1 half-tile; B-halves of cur are fully read in phase 0 -> safe at 2/3
            if (q == 0) { if (tn1) STAGE_A(nx, 0, k1); }
            if (q == 1) { if (tn1) STAGE_A(nx, 1, k1); }
            if (q == 2) { if (tn2) STAGE_B(cur, 0, k2); }
            if (q == 3) {
                if (tn2) {
                    STAGE_B(cur, 1, k2);
                    asm volatile("s_waitcnt vmcnt(4)" ::: "memory");  // tile tt+1 landed
                } else {
                    asm volatile("s_waitcnt vmcnt(0)" ::: "memory");  // tail drain
                }
            }
            __builtin_amdgcn_s_barrier();
            asm volatile("s_waitcnt lgkmcnt(0)" ::: "memory");
            __builtin_amdgcn_s_setprio(1);
#pragma unroll
            for (int kh = 0; kh < 2; ++kh)
#pragma unroll
                for (int nf = 0; nf < 4; ++nf) {
                    acc[2 * q][nf] = __builtin_amdgcn_mfma_f32_16x16x32_bf16(
                        aA[0][kh], bB[nf][kh], acc[2 * q][nf], 0, 0, 0);
                    acc[2 * q + 1][nf] = __builtin_amdgcn_mfma_f32_16x16x32_bf16(
                        aA[1][kh], bB[nf][kh], acc[2 * q + 1][nf], 0, 0, 0);
                }
            __builtin_amdgcn_s_setprio(0);
            __builtin_amdgcn_s_barrier();
        }
        cur = nx;
    }
#undef STAGE_A
#undef STAGE_B

    // C/D layout 16x16x32: col = lane&15, row = (lane>>4)*4 + reg
    float* Cp = Cpart + (size_t)blockIdx.z * MN;
    const int row0 = m0 + wrow * 128 + lq * 4;
    const int col0 = n0 + wcol * 64 + l15;
#pragma unroll
    for (int mf = 0; mf < 8; ++mf)
#pragma unroll
        for (int r = 0; r < 4; ++r) {
            float* p = Cp + (size_t)(row0 + mf * 16 + r) * N + col0;
            p[0]  = acc[mf][0][r];
            p[16] = acc[mf][1][r];
            p[32] = acc[mf][2][r];
            p[48] = acc[mf][3][r];
        }
}

// ---------------- bf16 GEMM, 128x128 tile, BK=64 (kept for the N=128 head GEMM) --------
__global__ __launch_bounds__(256) void k_gemm(const unsigned short* __restrict__ A,
                                              const unsigned short* __restrict__ BT,
                                              float* __restrict__ Cpart,
                                              int N, int K, int kChunk, int MN) {
    __shared__ __align__(16) unsigned short As[128 * 64];
    __shared__ __align__(16) unsigned short Bs[128 * 64];
    const int n0 = blockIdx.x * 128;
    const int m0 = blockIdx.y * 128;
    const int kBeg = blockIdx.z * kChunk;
    const int kEnd = kBeg + kChunk;
    const int t = threadIdx.x;
    const int lane = t & 63;
    const int wave = t >> 6;
    const int wm = (wave & 1) * 64;
    const int wn = (wave >> 1) * 64;
    const int l31 = lane & 31;
    const int half = lane >> 5;         // k-half 0..1
    const int xorb = l31 & 7;

    const int srow = t >> 3;
    const int sj = (t & 7) ^ (srow & 7);
    const unsigned short* ag = A + (size_t)(m0 + srow) * K + sj * 8;
    const unsigned short* bg = BT + (size_t)(n0 + srow) * K + sj * 8;
    char* alb = (char*)As + t * 16;
    char* blb = (char*)Bs + t * 16;
    const int rq = K * 32;              // +32 rows per q-step

    f32x16 acc[2][2] = {};
    const unsigned short* aBase = As + (wm + l31) * 64;
    const unsigned short* bBase = Bs + (wn + l31) * 64;

    for (int kt = kBeg; kt < kEnd; kt += 64) {
#pragma unroll
        for (int q = 0; q < 4; ++q) gld_lds16(ag + kt + q * rq, alb + q * 4096);
#pragma unroll
        for (int q = 0; q < 4; ++q) gld_lds16(bg + kt + q * rq, blb + q * 4096);
        __syncthreads();
#pragma unroll
        for (int s = 0; s < 4; ++s) {   // K=16 per step
            const int off = ((s * 2 + half) ^ xorb) * 8;
            bf16x8 a0 = *(const bf16x8*)(aBase + off);
            bf16x8 a1 = *(const bf16x8*)(aBase + 2048 + off);
            bf16x8 b0 = *(const bf16x8*)(bBase + off);
            bf16x8 b1 = *(const bf16x8*)(bBase + 2048 + off);
            acc[0][0] = __builtin_amdgcn_mfma_f32_32x32x16_bf16(a0, b0, acc[0][0], 0, 0, 0);
            acc[0][1] = __builtin_amdgcn_mfma_f32_32x32x16_bf16(a0, b1, acc[0][1], 0, 0, 0);
            acc[1][0] = __builtin_amdgcn_mfma_f32_32x32x16_bf16(a1, b0, acc[1][0], 0, 0, 0);
            acc[1][1] = __builtin_amdgcn_mfma_f32_32x32x16_bf16(a1, b1, acc[1][1], 0, 0, 0);
        }
        __syncthreads();
    }

    float* Cp = Cpart + (size_t)blockIdx.z * MN;
    const int colb = n0 + wn + l31;
    const int rbase = m0 + wm + 4 * half;
#pragma unroll
    for (int i = 0; i < 2; ++i)
#pragma unroll
        for (int j = 0; j < 2; ++j)
#pragma unroll
            for (int reg = 0; reg < 16; ++reg) {
                int row = rbase + i * 32 + (reg & 3) + 8 * (reg >> 2);
                Cp[(size_t)row * N + colb + j * 32] = acc[i][j][reg];
            }
}

// ---------------- 4-partial reduce + bias -> relu -> bf16 ------------------------------
__global__ __launch_bounds__(256) void k_bias_relu_cvt(const float* __restrict__ accP,
                                                       const float* __restrict__ bias,
                                                       unsigned short* __restrict__ out) {
    int gI = blockIdx.x * 256 + threadIdx.x;   // 1048576 float4s
    const float4* p = (const float4*)accP;
    float4 v0 = p[gI];
    float4 v1 = p[gI + 1048576];
    float4 v2 = p[gI + 2097152];
    float4 v3 = p[gI + 3145728];
    float4 b = ((const float4*)bias)[gI & 1023];
    ushort4 o;
    o.x = f2bf(fmaxf(v0.x + v1.x + v2.x + v3.x + b.x, 0.f));
    o.y = f2bf(fmaxf(v0.y + v1.y + v2.y + v3.y + b.y, 0.f));
    o.z = f2bf(fmaxf(v0.z + v1.z + v2.z + v3.z + b.z, 0.f));
    o.w = f2bf(fmaxf(v0.w + v1.w + v2.w + v3.w + b.w, 0.f));
    ((ushort4*)out)[gI] = o;
}

// ---------------- pack Wc (21) and Wr (80) transposed into [128][4096] bf16 ------------
__global__ __launch_bounds__(256) void k_pack_w3(const float* __restrict__ Wc,
                                                 const float* __restrict__ Wr,
                                                 unsigned short* __restrict__ W3T) {
    int gI = blockIdx.x * 256 + threadIdx.x;   // 128*4096
    int n = gI >> 12, k = gI & 4095;
    float v = 0.f;
    if (n < 21) v = Wc[k * 21 + n];
    else if (n < 101) v = Wr[k * 80 + (n - 21)];
    W3T[gI] = f2bf(v);
}

// ---------------- 16-partial reduce + softmax(cls) + reg writeout ----------------------
__global__ __launch_bounds__(64) void k_head(const float* __restrict__ acc3,
                                             const float* __restrict__ bc,
                                             const float* __restrict__ br,
                                             float* __restrict__ out) {
    int r = blockIdx.x;          // 1000
    int lane = threadIdx.x;
    float logit = -1e30f;
    if (lane < 21) {
        logit = bc[lane];
#pragma unroll
        for (int z = 0; z < 16; ++z) logit += acc3[z * 131072 + r * 128 + lane];
    }
    float mx = logit;
#pragma unroll
    for (int m = 32; m >= 1; m >>= 1) mx = fmaxf(mx, __shfl_xor(mx, m, 64));
    float e = (lane < 21) ? expf(logit - mx) : 0.f;
    float s = e;
#pragma unroll
    for (int m = 32; m >= 1; m >>= 1) s += __shfl_xor(s, m, 64);
    if (lane < 21) out[r * 21 + lane] = e / s;
    for (int j = lane; j < 80; j += 64) {
        float v = br[j];
#pragma unroll
        for (int z = 0; z < 16; ++z) v += acc3[z * 131072 + r * 128 + 21 + j];
        out[21000 + r * 80 + j] = v;
    }
}

extern "C" void kernel_launch(void* const* d_in, const int* in_sizes, int n_in,
                              void* d_out, int out_size, void* d_ws, size_t ws_size,
                              hipStream_t stream) {
    (void)in_sizes; (void)n_in; (void)out_size; (void)ws_size;
    const float* feats = (const float*)d_in[0];
    const float* props = (const float*)d_in[1];
    const float* W1    = (const float*)d_in[2];
    const float* b1    = (const float*)d_in[3];
    const float* W2    = (const float*)d_in[4];
    const float* b2    = (const float*)d_in[5];
    const float* Wc    = (const float*)d_in[6];
    const float* bc    = (const float*)d_in[7];
    const float* Wr    = (const float*)d_in[8];
    const float* br    = (const float*)d_in[9];
    float* out = (float*)d_out;

    char* ws = (char*)d_ws;
    unsigned short* W1T    = (unsigned short*)ws; ws += (size_t)4096 * 25088 * 2; // 205.5 MB
    unsigned short* W2T    = (unsigned short*)ws; ws += (size_t)4096 * 4096 * 2;  // 33.6 MB
    unsigned short* W3T    = (unsigned short*)ws; ws += (size_t)128 * 4096 * 2;   // 1.05 MB
    unsigned short* featsb = (unsigned short*)ws; ws += (size_t)972800 * 2;       // 1.95 MB
    unsigned short* pooled = (unsigned short*)ws; ws += (size_t)1024 * 25088 * 2; // 51.4 MB
    unsigned short* x1     = (unsigned short*)ws; ws += (size_t)1024 * 4096 * 2;  // 8.4 MB
    unsigned short* x2     = (unsigned short*)ws; ws += (size_t)1024 * 4096 * 2;  // 8.4 MB
    float* accP            = (float*)ws;          ws += (size_t)4 * 1024 * 4096 * 4; // 67.1 MB
    float* acc3P           = accP;  // GEMM3 partials reuse accP (free after bias2)

    k_cvt_feats<<<950, 256, 0, stream>>>(feats, featsb);
    k_roipool<<<1024 * 49, 256, 0, stream>>>(featsb, props, pooled);
    k_transpose_cvt<<<dim3(392, 64), 256, 0, stream>>>(W1, W1T, 25088, 4096);
    k_gemm256<<<dim3(16, 4, 4), 512, 0, stream>>>(pooled, W1T, accP, 4096, 25088, 6272, 1024 * 4096);
    k_bias_relu_cvt<<<4096, 256, 0, stream>>>(accP, b1, x1);
    k_transpose_cvt<<<dim3(64, 64), 256, 0, stream>>>(W2, W2T, 4096, 4096);
    k_gemm256<<<dim3(16, 4, 4), 512, 0, stream>>>(x1, W2T, accP, 4096, 4096, 1024, 1024 * 4096);
    k_bias_relu_cvt<<<4096, 256, 0, stream>>>(accP, b2, x2);
    k_pack_w3<<<2048, 256, 0, stream>>>(Wc, Wr, W3T);
    k_gemm<<<dim3(1, 8, 16), 256, 0, stream>>>(x2, W3T, acc3P, 128, 4096, 256, 1024 * 128);
    k_head<<<1000, 64, 0, stream>>>(acc3P, bc, br, out);
}